// Round 7
// baseline (257.543 us; speedup 1.0000x reference)
//
#include <hip/hip_runtime.h>

// AttributeDecoder: out[k,s,:] = feats[mask_idx[k,s],:] @ W[k] + b[k]. fp32.
// R9: R8 + A-fragment register pinning + dual MFMA accumulators.
//  R8 post-mortem: mkd VGPR_Count=52 < the 64 VGPRs the A-frags need =>
//  compiler rematerialized the A loads+bf16-conversions INSIDE the 12-hp loop
//  (12x scattered re-read of the A tile, ~1.6GB aggregate L1/L2 traffic) =>
//  latency-bound at 88us with all pipes idle. Fix:
//   (1) asm-opaque pin of each converted fragment (asm-defined values can't
//       be rematerialized) + __launch_bounds__(256,4) for <=128 VGPR.
//   (2) split the 24-deep serial MFMA chain into 2 independent 12-deep
//       chains (even/odd kb accumulators), merged with one vector add.
//  wk / gk / fallback unchanged (accuracy-verified in R7/R8).

#define KH 24
#define SS 16384
#define VV 8
#define DD 256
#define NROW 131072
#define NE (KH * SS)

typedef __attribute__((ext_vector_type(8))) short s16x8;
typedef __attribute__((ext_vector_type(4))) float f32x4;
typedef __attribute__((ext_vector_type(4))) unsigned int u32x4;

__device__ __forceinline__ unsigned short rne_bf16(float f) {
    unsigned u = __builtin_bit_cast(unsigned, f);
    unsigned r = u + 0x7FFFu + ((u >> 16) & 1u);
    return (unsigned short)(r >> 16);
}
__device__ __forceinline__ float bf16f(unsigned short h) {
    unsigned u = ((unsigned)h) << 16;
    return __builtin_bit_cast(float, u);
}

template <int CTRL>
__device__ __forceinline__ float dpp_mov(float x) {
    int xi = __builtin_bit_cast(int, x);
    int r = __builtin_amdgcn_update_dpp(xi, xi, CTRL, 0xF, 0xF, false);
    return __builtin_bit_cast(float, r);
}

// ---- wk: split W into bf16 hi/lo in MFMA B-fragment order (R7-verified) ----
// whi/wlo[((hp*8+kb)*64+lane)*8+j]: k = kb*32+(lane>>4)*8+j, n = lane&15,
// head = hp*2+(n>>3), v = n&7.
__global__ __launch_bounds__(256) void wk_kernel(
    const float* __restrict__ head_w, unsigned short* __restrict__ whi,
    unsigned short* __restrict__ wlo)
{
    const int idx = blockIdx.x * 256 + threadIdx.x;     // 0..49151
    const int j = idx & 7, lane = (idx >> 3) & 63;
    const int kb = (idx >> 9) & 7, hp = idx >> 12;
    const int head = hp * 2 + ((lane & 15) >> 3);
    const int v = lane & 7;
    const int k = kb * 32 + (lane >> 4) * 8 + j;
    const float f = head_w[((size_t)head * DD + k) * VV + v];
    const unsigned short hi = rne_bf16(f);
    whi[idx] = hi;
    wlo[idx] = rne_bf16(f - bf16f(hi));
}

// ---- mkd: dense 64-row tile -> logits[hp][row][16] ------------------------
__global__ __launch_bounds__(256, 4) void mkd_kernel(
    const float* __restrict__ feats,
    const unsigned short* __restrict__ whi,
    const unsigned short* __restrict__ wlo,
    float* __restrict__ logits)
{
    const int tid  = threadIdx.x;
    const int wave = tid >> 6;
    const int lane = tid & 63;
    const int m    = lane & 15;          // A row within 16-row subtile; D col
    const int kq   = lane >> 4;
    const int r0   = blockIdx.x * 64;

    __shared__ unsigned short Bbuf[2][8192];   // 2 x (8KB hi | 8KB lo)

    // Stage A: rows r0 + wave*16 + m, K=256 -> bf16 hi/lo frags, then PIN
    // each fragment as an asm-opaque value so the compiler cannot
    // rematerialize the loads/conversions inside the hp loop.
    const float* arow = feats + ((size_t)(r0 + wave * 16 + m)) * DD + kq * 8;
    s16x8 ahi[8], alo[8];
#pragma unroll
    for (int kb = 0; kb < 8; ++kb) {
        const float4 p = *(const float4*)(arow + kb * 32);
        const float4 q = *(const float4*)(arow + kb * 32 + 4);
        const float fv[8] = {p.x, p.y, p.z, p.w, q.x, q.y, q.z, q.w};
        s16x8 h, l;
#pragma unroll
        for (int j = 0; j < 8; ++j) {
            const unsigned short hi = rne_bf16(fv[j]);
            h[j] = (short)hi;
            l[j] = (short)rne_bf16(fv[j] - bf16f(hi));
        }
        u32x4 ph = __builtin_bit_cast(u32x4, h);
        u32x4 pl = __builtin_bit_cast(u32x4, l);
        asm volatile("" : "+v"(ph), "+v"(pl));      // register-pin
        ahi[kb] = __builtin_bit_cast(s16x8, ph);
        alo[kb] = __builtin_bit_cast(s16x8, pl);
    }

    // Prologue: stage hp=0 into buf0.
    {
        const uint4* sh = (const uint4*)(whi);
        const uint4* sl = (const uint4*)(wlo);
        uint4* bb = (uint4*)(&Bbuf[0][0]);
        bb[tid]       = sh[tid];
        bb[256 + tid] = sh[256 + tid];
        bb[512 + tid] = sl[tid];
        bb[768 + tid] = sl[256 + tid];
    }
    __syncthreads();

    for (int hp = 0; hp < 12; ++hp) {
        const int cur = hp & 1;

        // Issue next head-pair's B loads (land during compute; T14 split).
        uint4 t0, t1, t2, t3;
        const bool pf = (hp + 1) < 12;
        if (pf) {
            const uint4* sh = (const uint4*)(whi + (hp + 1) * 4096);
            const uint4* sl = (const uint4*)(wlo + (hp + 1) * 4096);
            t0 = sh[tid]; t1 = sh[256 + tid];
            t2 = sl[tid]; t3 = sl[256 + tid];
        }

        // Two independent 12-deep MFMA chains (even/odd kb).
        f32x4 c0 = {0.f, 0.f, 0.f, 0.f};
        f32x4 c1 = {0.f, 0.f, 0.f, 0.f};
#pragma unroll
        for (int kb = 0; kb < 8; kb += 2) {
            const s16x8 bh0 = *(const s16x8*)(&Bbuf[cur][kb * 512 + lane * 8]);
            const s16x8 bl0 = *(const s16x8*)(&Bbuf[cur][4096 + kb * 512 + lane * 8]);
            const s16x8 bh1 = *(const s16x8*)(&Bbuf[cur][(kb + 1) * 512 + lane * 8]);
            const s16x8 bl1 = *(const s16x8*)(&Bbuf[cur][4096 + (kb + 1) * 512 + lane * 8]);
            c0 = __builtin_amdgcn_mfma_f32_16x16x32_bf16(ahi[kb], bh0, c0, 0, 0, 0);
            c1 = __builtin_amdgcn_mfma_f32_16x16x32_bf16(ahi[kb + 1], bh1, c1, 0, 0, 0);
            c0 = __builtin_amdgcn_mfma_f32_16x16x32_bf16(alo[kb], bh0, c0, 0, 0, 0);
            c1 = __builtin_amdgcn_mfma_f32_16x16x32_bf16(alo[kb + 1], bh1, c1, 0, 0, 0);
            c0 = __builtin_amdgcn_mfma_f32_16x16x32_bf16(ahi[kb], bl0, c0, 0, 0, 0);
            c1 = __builtin_amdgcn_mfma_f32_16x16x32_bf16(ahi[kb + 1], bl1, c1, 0, 0, 0);
        }
        const f32x4 c = c0 + c1;

        // D[row=kq*4+rg][col=m] -> logits[hp][r0+wave*16+kq*4+rg][m]
        float* Lp = logits + ((size_t)hp * NROW + (r0 + wave * 16 + kq * 4)) * 16 + m;
#pragma unroll
        for (int rg = 0; rg < 4; ++rg)
            Lp[(size_t)rg * 16] = c[rg];

        if (pf) {
            uint4* bb = (uint4*)(&Bbuf[cur ^ 1][0]);
            bb[tid]       = t0;
            bb[256 + tid] = t1;
            bb[512 + tid] = t2;
            bb[768 + tid] = t3;
            __syncthreads();
        }
    }
}

// ---- gk: out[t] = logits[(hp*NROW+row)*16 + half*8 + v] + bias ------------
__global__ __launch_bounds__(256) void gk_kernel(
    const float* __restrict__ logits,
    const int* __restrict__ mask_idx,
    const float* __restrict__ head_b,
    float* __restrict__ out)
{
    const int t = blockIdx.x * 256 + threadIdx.x;       // 0 .. NE*8-1
    const int e = t >> 3;                               // (k,s) entry
    const int v = t & 7;
    const int k = e >> 14;
    const unsigned row = (unsigned)mask_idx[e];
    const int hp = k >> 1, half = k & 1;
    out[t] = logits[((size_t)hp * NROW + row) * 16 + half * 8 + v]
           + head_b[k * VV + v];
}

// ---------------- Fallback (verified R3) if workspace too small ------------
__global__ __launch_bounds__(256) void attr_decoder_fallback(
    const float* __restrict__ feats, const int* __restrict__ mask_idx,
    const float* __restrict__ head_w, const float* __restrict__ head_b,
    float* __restrict__ out)
{
    const int lane  = threadIdx.x & 63;
    const int wv    = __builtin_amdgcn_readfirstlane(threadIdx.x >> 6);
    const int k     = blockIdx.x >> 7;
    const int chunk = blockIdx.x & 127;
    const int lb    = lane & 7;

    const float* Wk = head_w + (size_t)k * (DD * VV);
    float w[4][8];
    {
        const bool q0 = (lane & 1) != 0;
        const bool q1 = (lane & 2) != 0;
        const bool q2 = (lane & 4) != 0;
#pragma unroll
        for (int t = 0; t < 4; ++t) {
            const float4 a = *(const float4*)(Wk + (lane * 4 + t) * VV);
            const float4 b = *(const float4*)(Wk + (lane * 4 + t) * VV + 4);
            const float x[8] = {a.x, a.y, a.z, a.w, b.x, b.y, b.z, b.w};
            float y[8], z[8];
#pragma unroll
            for (int j = 0; j < 8; ++j) y[j] = q0 ? x[j ^ 1] : x[j];
#pragma unroll
            for (int j = 0; j < 8; ++j) z[j] = q1 ? y[j ^ 2] : y[j];
#pragma unroll
            for (int j = 0; j < 8; ++j) w[t][j] = q2 ? z[j ^ 4] : z[j];
        }
    }
    const float bias = head_b[k * VV + lb];

    const char* fb = (const char*)feats;
    const int s_base = chunk * 128 + wv * 32;
    const int* mi = mask_idx + k * SS + s_base;
    float* outp = out + ((size_t)k * SS + s_base) * VV;
    const int vo = lane << 4;

    int4 rows = *(const int4*)mi;
    int r0 = __builtin_amdgcn_readfirstlane(rows.x);
    int r1 = __builtin_amdgcn_readfirstlane(rows.y);
    int r2 = __builtin_amdgcn_readfirstlane(rows.z);
    int r3 = __builtin_amdgcn_readfirstlane(rows.w);

    for (int i = 0; i < 32; i += 4) {
        const float4 f0 = *(const float4*)(fb + (((size_t)(unsigned)r0) << 10) + vo);
        const float4 f1 = *(const float4*)(fb + (((size_t)(unsigned)r1) << 10) + vo);
        const float4 f2 = *(const float4*)(fb + (((size_t)(unsigned)r2) << 10) + vo);
        const float4 f3 = *(const float4*)(fb + (((size_t)(unsigned)r3) << 10) + vo);
        if (i < 28) rows = *(const int4*)(mi + i + 4);

        float r[4];
        const float4 f[4] = {f0, f1, f2, f3};
#pragma unroll
        for (int u = 0; u < 4; ++u) {
            float acc[8];
#pragma unroll
            for (int v = 0; v < 8; ++v) {
                acc[v] = f[u].x * w[0][v];
                acc[v] = fmaf(f[u].y, w[1][v], acc[v]);
                acc[v] = fmaf(f[u].z, w[2][v], acc[v]);
                acc[v] = fmaf(f[u].w, w[3][v], acc[v]);
            }
            const float a40 = acc[0] + dpp_mov<0xB1>(acc[1]);
            const float a41 = acc[2] + dpp_mov<0xB1>(acc[3]);
            const float a42 = acc[4] + dpp_mov<0xB1>(acc[5]);
            const float a43 = acc[6] + dpp_mov<0xB1>(acc[7]);
            const float a20 = a40 + dpp_mov<0x4E>(a41);
            const float a21 = a42 + dpp_mov<0x4E>(a43);
            r[u] = a20 + __shfl_xor(a21, 4, 64);
        }
        r0 = __builtin_amdgcn_readfirstlane(rows.x);
        r1 = __builtin_amdgcn_readfirstlane(rows.y);
        r2 = __builtin_amdgcn_readfirstlane(rows.z);
        r3 = __builtin_amdgcn_readfirstlane(rows.w);

        const bool b3 = (lane & 8) != 0;
        const bool b4 = (lane & 16) != 0;
        const float t0 = (b3 ? r[1] : r[0]) + dpp_mov<0x128>(b3 ? r[0] : r[1]);
        const float t1 = (b3 ? r[3] : r[2]) + dpp_mov<0x128>(b3 ? r[2] : r[3]);
        float va = (b4 ? t1 : t0) + __shfl_xor(b4 ? t0 : t1, 16, 64);
        va += __shfl_xor(va, 32, 64);
        if (lane < 32) outp[i * VV + lane] = va + bias;
    }
}

extern "C" void kernel_launch(void* const* d_in, const int* in_sizes, int n_in,
                              void* d_out, int out_size, void* d_ws, size_t ws_size,
                              hipStream_t stream) {
    const float* feats    = (const float*)d_in[1];
    const int*   mask_idx = (const int*)  d_in[2];
    const float* head_w   = (const float*)d_in[3];
    const float* head_b   = (const float*)d_in[4];
    float* out = (float*)d_out;

    // Workspace layout (bytes):
    //   logits @ 0         : 12*131072*16*4 = 100663296
    //   whi    @ 100663296 : 49152*2        = 98304
    //   wlo    @ 100761600 : 98304
    const size_t need = 100663296u + 2u * 98304u;
    if (d_ws != nullptr && ws_size >= need) {
        char* ws = (char*)d_ws;
        float* logits = (float*)ws;
        unsigned short* whi = (unsigned short*)(ws + 100663296u);
        unsigned short* wlo = (unsigned short*)(ws + 100761600u);

        wk_kernel<<<dim3(192),   dim3(256), 0, stream>>>(head_w, whi, wlo);
        mkd_kernel<<<dim3(2048), dim3(256), 0, stream>>>(feats, whi, wlo, logits);
        gk_kernel<<<dim3(NE * VV / 256), dim3(256), 0, stream>>>(
            logits, mask_idx, head_b, out);
    } else {
        attr_decoder_fallback<<<dim3(KH * 128), dim3(256), 0, stream>>>(
            feats, mask_idx, head_w, head_b, out);
    }
}